// Round 2
// baseline (1196.464 us; speedup 1.0000x reference)
//
#include <hip/hip_runtime.h>
#include <hip/hip_bf16.h>

// Problem constants
#define TDATA 100000
#define NE 500
#define NI 200
#define SUB 20
#define NB 3
#define TSYN 201

// Layout
#define SROW 100552              // 200 front pad + data + 352 tail pad
#define HROW 216                 // conv taps padded: k in [-8,207] at [k+8]
#define NC_E 16                  // K chunks of 32 floats: 512 padded (K=500)
#define NC_I 7                   // 224 padded (K=200)
#define NBLK 782                 // ceil(3125 tiles / 4 waves-per-block)

// ws float offsets
#define OFF_HP  0                            // 2*20*216 = 8640 floats
#define OFF_BE  8640                         // e A-frags: 32*64*8 bf16 = 8192 float slots
#define OFF_BI  (OFF_BE + 8192)              // 16832; i A-frags: 14*64*8 bf16 = 3584 slots
#define OFF_INT (OFF_BI + 3584)              // 20416; inT = 40 rows x SROW
                                             // (inT row-0 front pad = guaranteed zeros,
                                             //  doubles as the OOB-redirect target)

typedef __bf16 bf16x8 __attribute__((ext_vector_type(8)));
typedef float  f32x16 __attribute__((ext_vector_type(16)));

// ---------------------------------------------------------------------------
// Setup: conv taps | inT pad zeros | bf16 A-operand fragments (exact MFMA
// per-lane order: element j of lane l, k-step u -> C[s=l&31][k=16u+8*(l>>5)+j])
// Grid = 212*256 = 54272 exactly.
// ---------------------------------------------------------------------------
__global__ __launch_bounds__(256) void setup_kernel(
    const float* __restrict__ C_e, const float* __restrict__ C_i,
    const float* __restrict__ K_syn, const float* __restrict__ tau_syn,
    const float* __restrict__ delta_syn, float* __restrict__ ws)
{
    int idx = blockIdx.x * 256 + threadIdx.x;
    if (idx < 8640) {                        // ---- conv taps (zero-padded)
        int c = idx / (SUB * HROW);
        int rem = idx - c * (SUB * HROW);
        int s = rem / HROW;
        int k = (rem - s * HROW) - 8;
        float v = 0.f;
        if (k >= 0 && k < TSYN) {
            float ts = (float)k - delta_syn[s * 2 + c];
            ts = ts < 0.f ? 0.f : ts;
            #pragma unroll
            for (int b = 0; b < NB; b++) {
                float tt = ts / expf(tau_syn[b * 2 + c]);
                v += K_syn[(s * NB + b) * 2 + c] * tt * expf(-tt);
            }
        }
        ws[OFF_HP + idx] = v;
    } else if (idx < 30720) {                // ---- inT front/tail pad zeros
        int j = idx - 8640;
        const int PERROW = 552;              // 200 front + 352 tail
        int row = j / PERROW;
        int e = j - row * PERROW;
        int off = (e < 200) ? e : (200 + TDATA + (e - 200));
        ws[OFF_INT + (long)row * SROW + off] = 0.f;
    } else if (idx < 47104) {                // ---- e A-frags (bf16), 32 k-steps
        int j = idx - 30720;                 // 32*64*8 = 16384
        int step = j >> 9;
        int lane = (j >> 3) & 63;
        int jj = j & 7;
        int k = step * 16 + ((lane >> 5) << 3) + jj;
        int s = lane & 31;
        float v = (s < SUB && k < NE) ? C_e[s * NE + k] : 0.f;
        ((__hip_bfloat16*)(ws + OFF_BE))[j] = (__hip_bfloat16)v;
    } else {                                 // ---- i A-frags (bf16), 14 k-steps
        int j = idx - 47104;                 // 14*64*8 = 7168
        int step = j >> 9;
        int lane = (j >> 3) & 63;
        int jj = j & 7;
        int k = step * 16 + ((lane >> 5) << 3) + jj;
        int s = lane & 31;
        float v = (s < SUB && k < NI) ? C_i[s * NI + k] : 0.f;
        ((__hip_bfloat16*)(ws + OFF_BI))[j] = (__hip_bfloat16)v;
    }
}

// ---------------------------------------------------------------------------
// MFMA GEMM v3: per-wave barrier-free pipeline with counted vmcnt.
//   wave = one 32-row tile, full K; K streamed in 4KB chunks (32 rows x 32
//   floats), double-buffered in the wave's private LDS slice; depth-2
//   prefetch, steady-state s_waitcnt vmcnt(4) (never 0 except last chunk).
//   LDS chunk layout [row][32] is XOR-swizzled via the GLOBAL source address
//   (global_load_lds dest must stay linear): slot(l) = 4*((l&7)^(l>>3));
//   read back at word n*32 + (k ^ ((n&7)<<2)) -> uniform 4 words/bank.
//   A-frags preloaded to registers (full unroll, static indices).
//   K-tail lanes redirect their source to a guaranteed-zero ws region
//   (matching A-frag zeros).
// ---------------------------------------------------------------------------
template<int K>
__device__ __forceinline__ void issue_chunk(
    const float* __restrict__ S, const float* __restrict__ zrp,
    long row0, int c, float* buf, int rsel, int slotl)
{
    #pragma unroll
    for (int q = 0; q < 4; q++) {            // each instr: 8 rows x 128B = 1KB
        const int kg = c * 32 + slotl;
        const float* src = (kg + 4 <= K)
            ? (S + (row0 + 8 * q + rsel) * (long)K + kg) : zrp;
        __builtin_amdgcn_global_load_lds(
            (const __attribute__((address_space(1))) char*)(const void*)src,
            (__attribute__((address_space(3))) char*)(void*)(buf + q * 256),
            16, 0, 0);
    }
}

template<int K, int NC>
__device__ __forceinline__ void gemm3_body(
    const float* __restrict__ S, const float* __restrict__ wsA,
    float* __restrict__ inT, const float* __restrict__ zrp,
    float* buf0, float* buf1, long tile, int lane)
{
    constexpr int NSTEP = 2 * NC;
    const long row0 = tile * 32;
    const int n = lane & 31, h = lane >> 5;
    const int rsel = lane >> 3;
    const int slotl = 4 * ((lane & 7) ^ rsel);
    const int xr = (n & 7) << 2;

    // A-frags -> registers (L2-hot 32KB region, shared by all waves)
    const bf16x8* afr = (const bf16x8*)wsA;
    bf16x8 A[NSTEP];
    #pragma unroll
    for (int u = 0; u < NSTEP; u++) A[u] = afr[u * 64 + lane];

    // prologue: chunks 0,1 in flight
    issue_chunk<K>(S, zrp, row0, 0, buf0, rsel, slotl);
    issue_chunk<K>(S, zrp, row0, 1, buf1, rsel, slotl);

    f32x16 acc = {};
    #pragma unroll
    for (int c = 0; c < NC; c++) {
        if (c < NC - 1) asm volatile("s_waitcnt vmcnt(4)" ::: "memory");
        else            asm volatile("s_waitcnt vmcnt(0)" ::: "memory");
        __builtin_amdgcn_sched_barrier(0);

        float* buf = (c & 1) ? buf1 : buf0;
        const float* r0 = buf + n * 32;
        bf16x8 bf[2];
        #pragma unroll
        for (int uu = 0; uu < 2; uu++) {
            const int kl = 16 * uu + 8 * h;
            float4 lo = *(const float4*)(r0 + (kl ^ xr));
            float4 hi = *(const float4*)(r0 + ((kl + 4) ^ xr));
            bf16x8 b;
            b[0] = (__bf16)lo.x; b[1] = (__bf16)lo.y; b[2] = (__bf16)lo.z; b[3] = (__bf16)lo.w;
            b[4] = (__bf16)hi.x; b[5] = (__bf16)hi.y; b[6] = (__bf16)hi.z; b[7] = (__bf16)hi.w;
            bf[uu] = b;
        }
        __builtin_amdgcn_sched_barrier(0);
        if (c + 2 < NC)                      // prefetch into the buffer just read
            issue_chunk<K>(S, zrp, row0, c + 2, buf, rsel, slotl);
        #pragma unroll
        for (int uu = 0; uu < 2; uu++)
            acc = __builtin_amdgcn_mfma_f32_32x32x16_bf16(A[2 * c + uu], bf[uu],
                                                          acc, 0, 0, 0);
    }

    // store: verified D layout col=lane&31, row=(r&3)+8*(r>>2)+4*h
    const long t = row0 + n;
    #pragma unroll
    for (int r = 0; r < 16; r++) {
        int m = (r & 3) + 8 * (r >> 2) + 4 * h;
        if (m < SUB)
            inT[(long)m * SROW + 200 + t] = acc[r];
    }
}

__global__ __launch_bounds__(256) void gemm_kernel(
    const float* __restrict__ Se, const float* __restrict__ Si,
    float* __restrict__ ws)
{
    __shared__ float lds[4][2][1024];        // 32KB: per-wave double buffer
    const int lane = threadIdx.x & 63, wave = threadIdx.x >> 6;
    if (blockIdx.x < NBLK) {
        long tile = (long)blockIdx.x * 4 + wave;
        if (tile >= 3125) return;            // no barriers -> safe early-out
        gemm3_body<NE, NC_E>(Se, ws + OFF_BE, ws + OFF_INT, ws + OFF_INT,
                             lds[wave][0], lds[wave][1], tile, lane);
    } else {
        long tile = (long)(blockIdx.x - NBLK) * 4 + wave;
        if (tile >= 3125) return;
        gemm3_body<NI, NC_I>(Si, ws + OFF_BI, ws + OFF_INT + (long)SUB * SROW,
                             ws + OFF_INT, lds[wave][0], lds[wave][1], tile, lane);
    }
}

// ---------------------------------------------------------------------------
// Conv v2: rolling 16-float register window, all LDS reads as ds_read_b128.
// Swizzle = 4-word skew  i + ((i>>5)<<2)  (16B-aligned, uniform 4 words/bank
// for the stride-8-lane float4 pattern).  Per group: 2 b128 new-data reads
// (vs 16 b32 before); ping-pong halves -> zero register moves.
// ---------------------------------------------------------------------------
#define SW(i) ((i) + (((i) >> 5) << 2))

#define CONV_G(G, LO, HI, DOLOAD) {                                        \
    float4 h0 = *(const float4*)&HT[c][8 * (G)];                           \
    float4 h1 = *(const float4*)&HT[c][8 * (G) + 4];                       \
    float hv[8] = {h0.x, h0.y, h0.z, h0.w, h1.x, h1.y, h1.z, h1.w};        \
    _Pragma("unroll")                                                      \
    for (int j = 0; j < 8; j++) {                                          \
        _Pragma("unroll")                                                  \
        for (int r = 0; r < 8; r++) {                                      \
            const int ix = 8 + r - j;                                      \
            acc[r] += hv[j] * ((ix < 8) ? LO[ix] : HI[ix - 8]);            \
        }                                                                  \
    }                                                                      \
    if (DOLOAD) {                                                          \
        const int a0 = wb + 216 - 8 * (G);                                 \
        *(float4*)&LO[0] = *(const float4*)&W[c][SW(a0)];                  \
        *(float4*)&LO[4] = *(const float4*)&W[c][SW(a0 + 4)];              \
    }                                                                      \
}

__global__ __launch_bounds__(256) void conv_kernel(
    const float* __restrict__ ws, float* __restrict__ out)
{
    __shared__ __align__(16) float W[2][2560];   // SW(2255)=2535 max
    __shared__ __align__(16) float HT[2][208];
    const int tid = threadIdx.x;
    const int s = blockIdx.y;
    const long t0 = (long)blockIdx.x * 2048;

    // stage windows: W[q] = row[t0 - 208 + q], q in [0,2256), b128 swizzled
    for (int i = tid; i < 1128; i += 256) {
        int cch = i >= 564;
        int i4 = i - cch * 564;
        float4 v = *(const float4*)(ws + OFF_INT + (long)(cch * SUB + s) * SROW
                                    + t0 - 8 + 4 * i4);
        *(float4*)&W[cch][SW(4 * i4)] = v;
    }
    if (tid < 104) {                          // taps: 2 channels x 208
        int cch = tid >= 52;
        int j4 = (tid - cch * 52) * 4;
        *(float4*)&HT[cch][j4] =
            *(const float4*)(ws + OFF_HP + (cch * SUB + s) * HROW + 8 + j4);
    }
    __syncthreads();

    float acc[8];
    #pragma unroll
    for (int r = 0; r < 8; r++) acc[r] = 0.f;
    const int wb = tid << 3;

    #pragma unroll
    for (int c = 0; c < 2; c++) {
        float xa[8], xb2[8];                  // window halves (ping-pong)
        *(float4*)&xa[0]  = *(const float4*)&W[c][SW(wb)];
        *(float4*)&xa[4]  = *(const float4*)&W[c][SW(wb + 4)];
        *(float4*)&xb2[0] = *(const float4*)&W[c][SW(wb + 8)];
        *(float4*)&xb2[4] = *(const float4*)&W[c][SW(wb + 12)];
        #pragma unroll
        for (int gg = 0; gg < 13; gg++) {
            const int g1 = 25 - 2 * gg, g0 = g1 - 1;
            CONV_G(g1, xa, xb2, 1);
            CONV_G(g0, xb2, xa, (g0 != 0));
        }
    }

    #pragma unroll
    for (int r = 0; r < 8; r++) {
        long t = t0 + 8 * tid + r;
        if (t < TDATA) out[t * SUB + s] = acc[r];
    }
}

// ---------------------------------------------------------------------------
extern "C" void kernel_launch(void* const* d_in, const int* in_sizes, int n_in,
                              void* d_out, int out_size, void* d_ws, size_t ws_size,
                              hipStream_t stream)
{
    const float* S_e     = (const float*)d_in[0];
    const float* S_i     = (const float*)d_in[1];
    const float* C_e     = (const float*)d_in[2];
    const float* C_i     = (const float*)d_in[3];
    const float* K_syn   = (const float*)d_in[4];
    const float* tau_syn = (const float*)d_in[5];
    const float* delta   = (const float*)d_in[6];
    float* out = (float*)d_out;
    float* ws  = (float*)d_ws;

    hipLaunchKernelGGL(setup_kernel, dim3(212), dim3(256), 0, stream,
                       C_e, C_i, K_syn, tau_syn, delta, ws);
    hipLaunchKernelGGL(gemm_kernel, dim3(2 * NBLK), dim3(256), 0, stream,
                       S_e, S_i, ws);
    hipLaunchKernelGGL(conv_kernel, dim3(49, SUB), dim3(256), 0, stream,
                       ws, out);
}

// Round 3
// 411.210 us; speedup vs baseline: 2.9096x; 2.9096x over previous
//
#include <hip/hip_runtime.h>
#include <hip/hip_bf16.h>

// Problem constants
#define TDATA 100000
#define NE 500
#define NI 200
#define SUB 20
#define NB 3
#define TSYN 201

// Layout
#define SROW 100552              // 200 front pad + data + 352 tail pad
#define HROW 216                 // conv taps padded: k in [-8,207] at [k+8]
#define NC_E 16                  // K chunks of 32 floats: 512 padded (K=500)
#define NC_I 7                   // 224 padded (K=200)
#define NGRP 782                 // ceil(3125 tiles / 4 waves-per-block)

// ws float offsets
#define OFF_HP  0                            // 2*20*216 = 8640 floats
#define OFF_BE  8640                         // e A-frags: 32*64*8 bf16 = 8192 float slots
#define OFF_BI  (OFF_BE + 8192)              // 16832; i A-frags: 14*64*8 bf16 = 3584 slots
#define OFF_INT (OFF_BI + 3584)              // 20416; inT = 40 rows x SROW
                                             // (inT row-0 front pad = guaranteed zeros,
                                             //  doubles as the OOB-redirect target)

typedef __bf16 bf16x8 __attribute__((ext_vector_type(8)));
typedef float  f32x16 __attribute__((ext_vector_type(16)));

// ---------------------------------------------------------------------------
// Setup: conv taps | inT pad zeros | bf16 A-operand fragments (exact MFMA
// per-lane order: element j of lane l, k-step u -> C[s=l&31][k=16u+8*(l>>5)+j])
// Grid = 212*256 = 54272 exactly.  (unchanged from round 2 — passed)
// ---------------------------------------------------------------------------
__global__ __launch_bounds__(256) void setup_kernel(
    const float* __restrict__ C_e, const float* __restrict__ C_i,
    const float* __restrict__ K_syn, const float* __restrict__ tau_syn,
    const float* __restrict__ delta_syn, float* __restrict__ ws)
{
    int idx = blockIdx.x * 256 + threadIdx.x;
    if (idx < 8640) {                        // ---- conv taps (zero-padded)
        int c = idx / (SUB * HROW);
        int rem = idx - c * (SUB * HROW);
        int s = rem / HROW;
        int k = (rem - s * HROW) - 8;
        float v = 0.f;
        if (k >= 0 && k < TSYN) {
            float ts = (float)k - delta_syn[s * 2 + c];
            ts = ts < 0.f ? 0.f : ts;
            #pragma unroll
            for (int b = 0; b < NB; b++) {
                float tt = ts / expf(tau_syn[b * 2 + c]);
                v += K_syn[(s * NB + b) * 2 + c] * tt * expf(-tt);
            }
        }
        ws[OFF_HP + idx] = v;
    } else if (idx < 30720) {                // ---- inT front/tail pad zeros
        int j = idx - 8640;
        const int PERROW = 552;              // 200 front + 352 tail
        int row = j / PERROW;
        int e = j - row * PERROW;
        int off = (e < 200) ? e : (200 + TDATA + (e - 200));
        ws[OFF_INT + (long)row * SROW + off] = 0.f;
    } else if (idx < 47104) {                // ---- e A-frags (bf16), 32 k-steps
        int j = idx - 30720;                 // 32*64*8 = 16384
        int step = j >> 9;
        int lane = (j >> 3) & 63;
        int jj = j & 7;
        int k = step * 16 + ((lane >> 5) << 3) + jj;
        int s = lane & 31;
        float v = (s < SUB && k < NE) ? C_e[s * NE + k] : 0.f;
        ((__hip_bfloat16*)(ws + OFF_BE))[j] = (__hip_bfloat16)v;
    } else {                                 // ---- i A-frags (bf16), 14 k-steps
        int j = idx - 47104;                 // 14*64*8 = 7168
        int step = j >> 9;
        int lane = (j >> 3) & 63;
        int jj = j & 7;
        int k = step * 16 + ((lane >> 5) << 3) + jj;
        int s = lane & 31;
        float v = (s < SUB && k < NI) ? C_i[s * NI + k] : 0.f;
        ((__hip_bfloat16*)(ws + OFF_BI))[j] = (__hip_bfloat16)v;
    }
}

// ---------------------------------------------------------------------------
// MFMA GEMM v3b: per-wave barrier-free pipeline with counted vmcnt.
//   wave = one 32-row tile, full K; K streamed in 4KB chunks (32 rows x 32
//   floats), double-buffered in the wave's private LDS slice; depth-2
//   prefetch, steady-state s_waitcnt vmcnt(4) (never 0 except last chunk).
//   LDS chunk layout [row][32] is XOR-swizzled via the GLOBAL source address
//   (global_load_lds dest must stay linear): slot(l) = 4*((l&7)^(l>>3));
//   read back at word n*32 + (k ^ ((n&7)<<2)).
//   A-frags preloaded to registers BEFORE the chunk prologue (vmcnt counts
//   stay consistent: at vmcnt(4) only chunk loads can be outstanding).
//   K-tail lanes redirect their source to a guaranteed-zero ws region.
//   NEW vs round 2: e/i tiles interleaved by block parity (load balance —
//   e is 71% of bytes and 2.3x the K-depth; all-e-then-all-i left i-CUs
//   idle in the tail).
// ---------------------------------------------------------------------------
template<int K>
__device__ __forceinline__ void issue_chunk(
    const float* __restrict__ S, const float* __restrict__ zrp,
    long row0, int c, float* buf, int rsel, int slotl)
{
    #pragma unroll
    for (int q = 0; q < 4; q++) {            // each instr: 8 rows x 128B = 1KB
        const int kg = c * 32 + slotl;
        const float* src = (kg + 4 <= K)
            ? (S + (row0 + 8 * q + rsel) * (long)K + kg) : zrp;
        __builtin_amdgcn_global_load_lds(
            (const __attribute__((address_space(1))) char*)(const void*)src,
            (__attribute__((address_space(3))) char*)(void*)(buf + q * 256),
            16, 0, 0);
    }
}

template<int K, int NC>
__device__ __forceinline__ void gemm3_body(
    const float* __restrict__ S, const float* __restrict__ wsA,
    float* __restrict__ inT, const float* __restrict__ zrp,
    float* buf0, float* buf1, long tile, int lane)
{
    constexpr int NSTEP = 2 * NC;
    const long row0 = tile * 32;
    const int n = lane & 31, h = lane >> 5;
    const int rsel = lane >> 3;
    const int slotl = 4 * ((lane & 7) ^ rsel);
    const int xr = (n & 7) << 2;

    // A-frags -> registers (L2-hot 16KB region, shared by all waves)
    const bf16x8* afr = (const bf16x8*)wsA;
    bf16x8 A[NSTEP];
    #pragma unroll
    for (int u = 0; u < NSTEP; u++) A[u] = afr[u * 64 + lane];

    // prologue: chunks 0,1 in flight
    issue_chunk<K>(S, zrp, row0, 0, buf0, rsel, slotl);
    issue_chunk<K>(S, zrp, row0, 1, buf1, rsel, slotl);

    f32x16 acc = {};
    #pragma unroll
    for (int c = 0; c < NC; c++) {
        if (c < NC - 1) asm volatile("s_waitcnt vmcnt(4)" ::: "memory");
        else            asm volatile("s_waitcnt vmcnt(0)" ::: "memory");
        __builtin_amdgcn_sched_barrier(0);

        float* buf = (c & 1) ? buf1 : buf0;
        const float* r0 = buf + n * 32;
        bf16x8 bf[2];
        #pragma unroll
        for (int uu = 0; uu < 2; uu++) {
            const int kl = 16 * uu + 8 * h;
            float4 lo = *(const float4*)(r0 + (kl ^ xr));
            float4 hi = *(const float4*)(r0 + ((kl + 4) ^ xr));
            bf16x8 b;
            b[0] = (__bf16)lo.x; b[1] = (__bf16)lo.y; b[2] = (__bf16)lo.z; b[3] = (__bf16)lo.w;
            b[4] = (__bf16)hi.x; b[5] = (__bf16)hi.y; b[6] = (__bf16)hi.z; b[7] = (__bf16)hi.w;
            bf[uu] = b;
        }
        __builtin_amdgcn_sched_barrier(0);
        if (c + 2 < NC)                      // prefetch into the buffer just read
            issue_chunk<K>(S, zrp, row0, c + 2, buf, rsel, slotl);
        #pragma unroll
        for (int uu = 0; uu < 2; uu++)
            acc = __builtin_amdgcn_mfma_f32_32x32x16_bf16(A[2 * c + uu], bf[uu],
                                                          acc, 0, 0, 0);
    }

    // store: verified D layout col=lane&31, row=(r&3)+8*(r>>2)+4*h
    const long t = row0 + n;
    #pragma unroll
    for (int r = 0; r < 16; r++) {
        int m = (r & 3) + 8 * (r >> 2) + 4 * h;
        if (m < SUB)
            inT[(long)m * SROW + 200 + t] = acc[r];
    }
}

__global__ __launch_bounds__(256) void gemm_kernel(
    const float* __restrict__ Se, const float* __restrict__ Si,
    float* __restrict__ ws)
{
    __shared__ float lds[4][2][1024];        // 32KB: per-wave double buffer
    const int lane = threadIdx.x & 63, wave = threadIdx.x >> 6;
    const int half = blockIdx.x & 1;         // interleave e/i for balance
    const long tile = (long)(blockIdx.x >> 1) * 4 + wave;
    if (tile >= 3125) return;                // no barriers -> safe early-out
    if (!half)
        gemm3_body<NE, NC_E>(Se, ws + OFF_BE, ws + OFF_INT, ws + OFF_INT,
                             lds[wave][0], lds[wave][1], tile, lane);
    else
        gemm3_body<NI, NC_I>(Si, ws + OFF_BI, ws + OFF_INT + (long)SUB * SROW,
                             ws + OFF_INT, lds[wave][0], lds[wave][1], tile, lane);
}

// ---------------------------------------------------------------------------
// Conv: REVERTED to the round-0/1 version (benched clean twice; round-2's
// rolling-window rewrite spilled to scratch: VGPR 256, 1.43GB fetch, 864us).
// block = (s, 2048 t's); windows staged in LDS with i+(i>>5) swizzle
// (raw stride-8 lane pattern would be 16-way bank-conflicted); taps in LDS,
// broadcast ds_read_b128. Thread = 8 consecutive t's; 16-float reg window
// per 8-tap group -> 64 fmac per 16 LDS b32 reads. No s_load in loop.
// ---------------------------------------------------------------------------
#define SW(i) ((i) + ((i) >> 5))

__global__ __launch_bounds__(256) void conv_kernel(
    const float* __restrict__ ws, float* __restrict__ out)
{
    __shared__ __align__(16) float W[2][2336];   // SW(2255)=2325 max
    __shared__ __align__(16) float HT[2][208];
    const int tid = threadIdx.x;
    const int s = blockIdx.y;
    const long t0 = (long)blockIdx.x * 2048;

    // stage windows: W[c][q] = row_c[t0 - 208 + q], q in [0,2256)
    for (int i = tid; i < 1128; i += 256) {
        int c = i >= 564;
        int i4 = i - c * 564;
        float4 v = *(const float4*)(ws + OFF_INT + (long)(c * SUB + s) * SROW
                                    + t0 - 8 + 4 * i4);
        int b = 4 * i4;
        int p = SW(b);                        // contiguous within aligned-4 runs
        W[c][p] = v.x; W[c][p + 1] = v.y; W[c][p + 2] = v.z; W[c][p + 3] = v.w;
    }
    if (tid < 104) {                          // taps: 2 channels x 208
        int c = tid >= 52;
        int j4 = (tid - c * 52) * 4;
        *(float4*)&HT[c][j4] =
            *(const float4*)(ws + OFF_HP + (c * SUB + s) * HROW + 8 + j4);
    }
    __syncthreads();

    float acc[8];
    #pragma unroll
    for (int r = 0; r < 8; r++) acc[r] = 0.f;

    #pragma unroll
    for (int c = 0; c < 2; c++) {
        #pragma unroll 2
        for (int g = 0; g < 26; g++) {
            int k0 = g << 3;
            int xb = (tid << 3) + 200 - k0;
            float x[16];
            #pragma unroll
            for (int q = 0; q < 16; q++) x[q] = W[c][SW(xb + q)];
            float h[8];
            *(float4*)&h[0] = *(const float4*)&HT[c][k0];
            *(float4*)&h[4] = *(const float4*)&HT[c][k0 + 4];
            #pragma unroll
            for (int j = 0; j < 8; j++)
                #pragma unroll
                for (int r = 0; r < 8; r++)
                    acc[r] += h[j] * x[8 + r - j];
        }
    }

    #pragma unroll
    for (int r = 0; r < 8; r++) {
        long t = t0 + 8 * tid + r;
        if (t < TDATA) out[t * SUB + s] = acc[r];
    }
}

// ---------------------------------------------------------------------------
extern "C" void kernel_launch(void* const* d_in, const int* in_sizes, int n_in,
                              void* d_out, int out_size, void* d_ws, size_t ws_size,
                              hipStream_t stream)
{
    const float* S_e     = (const float*)d_in[0];
    const float* S_i     = (const float*)d_in[1];
    const float* C_e     = (const float*)d_in[2];
    const float* C_i     = (const float*)d_in[3];
    const float* K_syn   = (const float*)d_in[4];
    const float* tau_syn = (const float*)d_in[5];
    const float* delta   = (const float*)d_in[6];
    float* out = (float*)d_out;
    float* ws  = (float*)d_ws;

    hipLaunchKernelGGL(setup_kernel, dim3(212), dim3(256), 0, stream,
                       C_e, C_i, K_syn, tau_syn, delta, ws);
    hipLaunchKernelGGL(gemm_kernel, dim3(2 * NGRP), dim3(256), 0, stream,
                       S_e, S_i, ws);
    hipLaunchKernelGGL(conv_kernel, dim3(49, SUB), dim3(256), 0, stream,
                       ws, out);
}